// Round 1
// baseline (828.880 us; speedup 1.0000x reference)
//
#include <hip/hip_runtime.h>

// NeighborCorrelator: out[b, 7i+j, h, w] =
//   inv_nx[b,h,w] * inv_ny[b,h+i-3,w+j-3] * sum_c x[b,c,h,w]*y[b,c,h+i-3,w+j-3]
// Normalizers factor out of the channel dot -> single fused pass.
// MFMA formulation: per (h-row, i): G[w1][w2] = sum_c X[c,w1]*Y_i[c,w2] via
// 16x16x32 bf16 MFMA over a 22-wide (zero-padded to 32) w2 window; keep
// diagonals j = w2 - w1 in [0,7).

#define H_ 256
#define W_ 256
#define C_ 256
#define B_ 4
#define TH 16
#define TW 16
#define KCH 32             // channels per LDS chunk
#define NCHUNK (C_ / KCH)  // 8
#define HAL (TH + 6)       // 22
#define WAL (TW + 6)       // 22
#define YW 32              // padded w2 extent (2 MFMA N-tiles)
#define PLANE (H_ * W_)    // 65536

typedef __attribute__((ext_vector_type(8))) short short8;
typedef __attribute__((ext_vector_type(4))) float floatx4;

// pack two floats to bf16x2 (RNE), a -> low half (even channel)
__device__ __forceinline__ unsigned bfpair(float a, float b) {
  unsigned ua = __float_as_uint(a), ub = __float_as_uint(b);
  ua = (ua + 0x7FFFu + ((ua >> 16) & 1u)) >> 16;
  ub = (ub + 0x7FFFu + ((ub >> 16) & 1u)) & 0xFFFF0000u;
  return ub | ua;
}

__global__ __launch_bounds__(1024) void ncorr(const float* __restrict__ x,
                                              const float* __restrict__ y,
                                              float* __restrict__ out) {
  // LDS: 45056 + 16384 + 1024 + 1936 = 64400 B
  __shared__ short Yb[HAL * YW * KCH];  // [hy][w2(32)][c32] bf16
  __shared__ short Xb[TH * TW * KCH];   // [h][w][c32] bf16
  __shared__ float sxl[TH * TW];        // sum x^2 per (h,w)
  __shared__ float syl[HAL * WAL];      // sum y^2 per (hy,wy)

  const int t = threadIdx.x;
  const int b = blockIdx.z;
  const int h0 = blockIdx.y * TH;
  const int w0 = blockIdx.x * TW;

  // ---- zero the Yb pad columns (w2 in [22,32)) once; they are never staged ----
  for (int idx = t; idx < HAL * 10 * (KCH / 2); idx += 1024) {
    int hy = idx / (10 * (KCH / 2));
    int r = idx - hy * (10 * (KCH / 2));
    int wy = 22 + r / (KCH / 2);
    int cp = r - (r / (KCH / 2)) * (KCH / 2);
    ((unsigned*)Yb)[((hy * YW + wy) * KCH) / 2 + cp] = 0u;
  }
  if (t < TH * TW) sxl[t] = 0.f;
  if (t < HAL * WAL) syl[t] = 0.f;

  // ---- staging slot precompute ----
  // X: 4096 bf16-pair slots = 16 cpair x 16 h x 16 w ; 4 per thread
  int xidx[4], xlds[4];
  float sxacc[4];
#pragma unroll
  for (int i = 0; i < 4; i++) {
    int s = t + i * 1024;
    int cp = s >> 8;
    int h = (s >> 4) & 15;
    int w = s & 15;
    xidx[i] = ((b * C_ + 2 * cp) * H_ + (h0 + h)) * W_ + (w0 + w);
    xlds[i] = (h * TW + w) * KCH + 2 * cp;
    sxacc[i] = 0.f;
  }
  // Y: 7744 slots = 16 cpair x 22 hy x 22 wy ; up to 8 per thread
  int yidx[8], ylds[8], ysl[8];
  float syacc[8];
  unsigned yok = 0;  // bit i: slot inside image (load), else staged as 0
#pragma unroll
  for (int i = 0; i < 8; i++) {
    int s = t + i * 1024;
    int cp = s / 484;
    int r = s - cp * 484;
    int hy = r / 22;
    int wy = r - hy * 22;
    int gy = h0 - 3 + hy;
    int gx = w0 - 3 + wy;
    bool inimg = (gy >= 0) && (gy < H_) && (gx >= 0) && (gx < W_);
    if (inimg) yok |= (1u << i);
    yidx[i] = ((b * C_ + 2 * cp) * H_ + (inimg ? gy : 0)) * W_ + (inimg ? gx : 0);
    ylds[i] = (hy * YW + wy) * KCH + 2 * cp;
    ysl[i] = r;
    syacc[i] = 0.f;
  }

  const int lane = t & 63;
  const int wv = t >> 6;  // wave id == local h row
  const int q = lane >> 4;
  const int lr = lane & 15;

  floatx4 acc[7][2];
#pragma unroll
  for (int i = 0; i < 7; i++) {
    acc[i][0] = (floatx4){0.f, 0.f, 0.f, 0.f};
    acc[i][1] = (floatx4){0.f, 0.f, 0.f, 0.f};
  }

  for (int ch = 0; ch < NCHUNK; ch++) {
    __syncthreads();  // protect LDS from previous iteration's readers
    const int coff = ch * (KCH * PLANE);
    // stage X tile (always fully in-image)
#pragma unroll
    for (int i = 0; i < 4; i++) {
      const float* p = x + xidx[i] + coff;
      float f0 = p[0], f1 = p[PLANE];
      sxacc[i] += f0 * f0 + f1 * f1;
      *(unsigned*)&Xb[xlds[i]] = bfpair(f0, f1);
    }
    // stage Y halo window (image-OOB -> 0)
#pragma unroll
    for (int i = 0; i < 8; i++) {
      if (i == 7 && t >= 576) break;  // slots 7744..8191 don't exist
      float f0 = 0.f, f1 = 0.f;
      if ((yok >> i) & 1) {
        const float* p = y + yidx[i] + coff;
        f0 = p[0];
        f1 = p[PLANE];
      }
      syacc[i] += f0 * f0 + f1 * f1;
      *(unsigned*)&Yb[ylds[i]] = bfpair(f0, f1);
    }
    __syncthreads();
    // compute: wave wv handles output h-row h0+wv
    // A frag: A[m=lr][k=q*8+j] = Xb[wv][lr][q*8..+8]
    short8 A = *(const short8*)&Xb[(wv * TW + lr) * KCH + q * 8];
#pragma unroll
    for (int i = 0; i < 7; i++) {
      const int hy = wv + i;  // y halo row for offset i
#pragma unroll
      for (int nt = 0; nt < 2; nt++) {
        // B frag: B[k=q*8+j][n=nt*16+lr] = Yb[hy][nt*16+lr][q*8..+8]
        short8 Bf = *(const short8*)&Yb[(hy * YW + nt * 16 + lr) * KCH + q * 8];
        acc[i][nt] = __builtin_amdgcn_mfma_f32_16x16x32_bf16(A, Bf, acc[i][nt], 0, 0, 0);
      }
    }
  }

  // ---- reduce norms ----
  __syncthreads();
#pragma unroll
  for (int i = 0; i < 4; i++) atomicAdd(&sxl[(t + i * 1024) & 255], sxacc[i]);
#pragma unroll
  for (int i = 0; i < 8; i++) {
    if (i == 7 && t >= 576) break;
    atomicAdd(&syl[ysl[i]], syacc[i]);
  }
  __syncthreads();
  if (t < TH * TW) sxl[t] = 1.f / fmaxf(sqrtf(sxl[t]), 1e-12f);
  if (t < HAL * WAL) syl[t] = 1.f / fmaxf(sqrtf(syl[t]), 1e-12f);
  __syncthreads();

  // ---- epilogue: C/D layout col(n)=lane&15 (+16*nt), row(m)=q*4+r ----
  const int h = wv;
#pragma unroll
  for (int i = 0; i < 7; i++) {
#pragma unroll
    for (int nt = 0; nt < 2; nt++) {
      const int n = nt * 16 + lr;  // w2 window index
#pragma unroll
      for (int r = 0; r < 4; r++) {
        const int m = q * 4 + r;  // output w index within tile
        const int j = n - m;      // kernel w-offset
        if (j >= 0 && j < 7) {
          float v = acc[i][nt][r] * sxl[h * TW + m] * syl[(h + i) * WAL + n];
          out[((b * 49 + 7 * i + j) * H_ + (h0 + h)) * W_ + (w0 + m)] = v;
        }
      }
    }
  }
}

extern "C" void kernel_launch(void* const* d_in, const int* in_sizes, int n_in,
                              void* d_out, int out_size, void* d_ws, size_t ws_size,
                              hipStream_t stream) {
  const float* x = (const float*)d_in[0];
  const float* y = (const float*)d_in[1];
  float* out = (float*)d_out;
  dim3 grid(W_ / TW, H_ / TH, B_);
  ncorr<<<grid, 1024, 0, stream>>>(x, y, out);
}